// Round 1
// baseline (2071.318 us; speedup 1.0000x reference)
//
#include <hip/hip_runtime.h>

#define NNODES 100000
#define NEDGES 3200000
#define FEAT 32
#define NITER 5
#define NF (NNODES * FEAT)

// ---------------- precompute: edge weights, compaction, masked-sum ----------------
// Unmasked edges -> compact (src, dst, w) lists via wave-aggregated atomic append.
// Masked edges (src=dst=0 after mask) -> scalar S = sum of their weights.
__global__ void precompute_kernel(const int* __restrict__ edge_index,
                                  const int* __restrict__ edge_mask,
                                  const float* __restrict__ edge_scale,
                                  const float* __restrict__ pert_mask,
                                  const float* __restrict__ edge_weight,
                                  int* __restrict__ csrc,
                                  int* __restrict__ cdst,
                                  float* __restrict__ cw,
                                  int* __restrict__ cnt,
                                  float* __restrict__ S) {
    const int tid = blockIdx.x * blockDim.x + threadIdx.x;
    const int stride = gridDim.x * blockDim.x;
    const int lane = threadIdx.x & 63;
    // pad trip count so all lanes of a wave iterate together (ballot/shfl safe)
    const int epad = ((NEDGES + stride - 1) / stride) * stride;

    for (int e = tid; e < epad; e += stride) {
        const bool valid = (e < NEDGES);
        int   m  = valid ? edge_mask[e] : 0;
        float ew = valid ? edge_weight[e] : 0.0f;
        float pm = valid ? pert_mask[e] : 0.0f;
        float es = valid ? edge_scale[e] : 0.0f;
        float w = (ew * (1.0f - pm) + pm) * es;

        const bool keep = valid && (m != 0);
        unsigned long long ball = __ballot(keep);
        if (ball) {
            int nk = __popcll(ball);
            int leader = __ffsll((long long)ball) - 1;
            int base = 0;
            if (lane == leader) base = atomicAdd(cnt, nk);
            base = __shfl(base, leader);
            if (keep) {
                int pos = base + __popcll(ball & ((1ull << lane) - 1ull));
                csrc[pos] = edge_index[e];           // row 0: src
                cdst[pos] = edge_index[NEDGES + e];  // row 1: dst
                cw[pos] = w;
            }
        }
        // masked-edge weight sum (these all send w*x[0] into node 0)
        float ms = (valid && m == 0) ? w : 0.0f;
        for (int o = 32; o; o >>= 1) ms += __shfl_xor(ms, o);
        if (lane == 0 && ms != 0.0f) atomicAdd(S, ms);
    }
}

// ---------------- scatter: acc[dst] += w * x[src] over compacted edges ----------------
__global__ void scatter_kernel(const float* __restrict__ x,
                               const int* __restrict__ csrc,
                               const int* __restrict__ cdst,
                               const float* __restrict__ cw,
                               const int* __restrict__ cnt,
                               const float* __restrict__ S,
                               float* __restrict__ acc) {
    // masked-edge bulk contribution to node 0 (once per iteration)
    if (blockIdx.x == 0 && threadIdx.x < FEAT) {
        atomicAdd(&acc[threadIdx.x], S[0] * x[threadIdx.x]);
    }
    const int cn = *cnt;
    const int total = cn * FEAT;          // <= 102.4M, fits int32
    const int stride = gridDim.x * blockDim.x;
    for (int i = blockIdx.x * blockDim.x + threadIdx.x; i < total; i += stride) {
        const int e = i >> 5;       // FEAT == 32
        const int f = i & 31;
        const int s = csrc[e];
        const int d = cdst[e];
        const float w = cw[e];
        atomicAdd(&acc[d * FEAT + f], w * x[s * FEAT + f]);
    }
}

// ---------------- update: x' = clip(x + clip(acc - x, -1, 1), 0, 2); acc = 0 ----------------
__global__ void update_kernel(const float* __restrict__ xin,
                              float* __restrict__ acc,
                              float* __restrict__ xout) {
    const int total4 = NF / 4;
    const int stride = gridDim.x * blockDim.x;
    const float4 zero4 = make_float4(0.f, 0.f, 0.f, 0.f);
    for (int i = blockIdx.x * blockDim.x + threadIdx.x; i < total4; i += stride) {
        float4 a = reinterpret_cast<float4*>(acc)[i];
        float4 xo = reinterpret_cast<const float4*>(xin)[i];
        float4 r;
        {
            float d0 = fminf(fmaxf(a.x - xo.x, -1.f), 1.f);
            float d1 = fminf(fmaxf(a.y - xo.y, -1.f), 1.f);
            float d2 = fminf(fmaxf(a.z - xo.z, -1.f), 1.f);
            float d3 = fminf(fmaxf(a.w - xo.w, -1.f), 1.f);
            r.x = fminf(fmaxf(xo.x + d0, 0.f), 2.f);
            r.y = fminf(fmaxf(xo.y + d1, 0.f), 2.f);
            r.z = fminf(fmaxf(xo.z + d2, 0.f), 2.f);
            r.w = fminf(fmaxf(xo.w + d3, 0.f), 2.f);
        }
        reinterpret_cast<float4*>(xout)[i] = r;
        reinterpret_cast<float4*>(acc)[i] = zero4;   // pre-zero for next iteration
    }
}

extern "C" void kernel_launch(void* const* d_in, const int* in_sizes, int n_in,
                              void* d_out, int out_size, void* d_ws, size_t ws_size,
                              hipStream_t stream) {
    const float* x0        = (const float*)d_in[0];
    const int*   edge_index= (const int*)d_in[1];
    const int*   edge_mask = (const int*)d_in[2];
    const float* edge_scale= (const float*)d_in[3];
    const float* pert_mask = (const float*)d_in[4];
    const float* edge_weight=(const float*)d_in[5];
    float* xout = (float*)d_out;

    // workspace layout (all 16B-aligned)
    char* ws = (char*)d_ws;
    int*   cnt   = (int*)ws;                       // [0,4)
    float* S     = (float*)(ws + 16);              // [16,20)
    float* acc   = (float*)(ws + 64);              // NF floats = 12.8 MB
    float* x_mid = (float*)(ws + 64 + (size_t)NF * 4);
    char*  edges = ws + 64 + (size_t)NF * 8;
    int*   csrc  = (int*)edges;
    int*   cdst  = (int*)(edges + (size_t)NEDGES * 4);
    float* cw    = (float*)(edges + (size_t)NEDGES * 8);
    // total ~64.1 MB

    hipMemsetAsync(ws, 0, 64, stream);                        // cnt, S
    hipMemsetAsync(acc, 0, (size_t)NF * 4, stream);           // accumulator

    precompute_kernel<<<2048, 256, 0, stream>>>(edge_index, edge_mask, edge_scale,
                                                pert_mask, edge_weight,
                                                csrc, cdst, cw, cnt, S);

    // ping-pong: in -> out -> mid -> out -> mid -> out   (5 iterations, ends in d_out)
    const float* cur = x0;
    float* bufs[NITER] = { xout, x_mid, xout, x_mid, xout };
    for (int it = 0; it < NITER; ++it) {
        scatter_kernel<<<4096, 256, 0, stream>>>(cur, csrc, cdst, cw, cnt, S, acc);
        update_kernel<<<2048, 256, 0, stream>>>(cur, acc, bufs[it]);
        cur = bufs[it];
    }
}

// Round 2
// 595.742 us; speedup vs baseline: 3.4769x; 3.4769x over previous
//
#include <hip/hip_runtime.h>

#define NNODES 100000
#define NEDGES 3200000
#define FEAT 32
#define NITER 5
#define NF (NNODES * FEAT)

#define SCAN_BLK 1024
#define NB1 98              // ceil(100000/1024); 98*1024 = 100352
#define NPAD (NB1 * SCAN_BLK)
#define HIST_BLOCKS ((NEDGES + 255) / 256)   // 12500

// ---- pass A: dst histogram (unmasked) + per-block masked-weight partial sums ----
__global__ void hist_kernel(const int* __restrict__ edge_index,
                            const int* __restrict__ edge_mask,
                            const float* __restrict__ edge_scale,
                            const float* __restrict__ pert_mask,
                            const float* __restrict__ edge_weight,
                            int* __restrict__ counts,
                            float* __restrict__ S_part) {
    const int e = blockIdx.x * 256 + threadIdx.x;
    float ms = 0.0f;
    if (e < NEDGES) {
        const int m = edge_mask[e];
        const float w = (edge_weight[e] * (1.0f - pert_mask[e]) + pert_mask[e]) * edge_scale[e];
        if (m) {
            atomicAdd(&counts[edge_index[NEDGES + e]], 1);
        } else {
            ms = w;   // masked edge: contributes w * x[0] to node 0
        }
    }
    __shared__ float s[256];
    s[threadIdx.x] = ms;
    __syncthreads();
    for (int off = 128; off; off >>= 1) {
        if (threadIdx.x < off) s[threadIdx.x] += s[threadIdx.x + off];
        __syncthreads();
    }
    if (threadIdx.x == 0) S_part[blockIdx.x] = s[0];
}

// ---- deterministic reduce of S partials ----
__global__ void sreduce_kernel(const float* __restrict__ S_part, float* __restrict__ S) {
    __shared__ float s[1024];
    float a = 0.0f;
    for (int i = threadIdx.x; i < HIST_BLOCKS; i += 1024) a += S_part[i];
    s[threadIdx.x] = a;
    __syncthreads();
    for (int off = 512; off; off >>= 1) {
        if (threadIdx.x < off) s[threadIdx.x] += s[threadIdx.x + off];
        __syncthreads();
    }
    if (threadIdx.x == 0) *S = s[0];
}

// ---- scan stage 1: per-block sums ----
__global__ void scan1_kernel(const int* __restrict__ counts, int* __restrict__ bsum) {
    __shared__ int s[SCAN_BLK];
    const int i = blockIdx.x * SCAN_BLK + threadIdx.x;
    s[threadIdx.x] = counts[i];
    __syncthreads();
    for (int off = SCAN_BLK / 2; off; off >>= 1) {
        if (threadIdx.x < off) s[threadIdx.x] += s[threadIdx.x + off];
        __syncthreads();
    }
    if (threadIdx.x == 0) bsum[blockIdx.x] = s[0];
}

// ---- scan stage 2: exclusive scan of block sums (single block, 128 threads) ----
__global__ void scan2_kernel(const int* __restrict__ bsum, int* __restrict__ boff) {
    __shared__ int s[128];
    const int tid = threadIdx.x;
    int v = (tid < NB1) ? bsum[tid] : 0;
    s[tid] = v;
    __syncthreads();
    for (int off = 1; off < 128; off <<= 1) {
        int t = (tid >= off) ? s[tid - off] : 0;
        __syncthreads();
        s[tid] += t;
        __syncthreads();
    }
    if (tid < NB1) boff[tid] = s[tid] - v;   // exclusive
}

// ---- scan stage 3: per-block exclusive scan + offset -> row_ptr, wp ----
__global__ void scan3_kernel(const int* __restrict__ counts, const int* __restrict__ boff,
                             int* __restrict__ row_ptr, int* __restrict__ wp) {
    __shared__ int s[SCAN_BLK];
    const int tid = threadIdx.x;
    const int i = blockIdx.x * SCAN_BLK + tid;
    const int v = counts[i];
    s[tid] = v;
    __syncthreads();
    for (int off = 1; off < SCAN_BLK; off <<= 1) {
        int t = (tid >= off) ? s[tid - off] : 0;
        __syncthreads();
        s[tid] += t;
        __syncthreads();
    }
    const int excl = boff[blockIdx.x] + s[tid] - v;
    if (i <= NNODES) row_ptr[i] = excl;
    if (i < NNODES)  wp[i] = excl;
}

// ---- fill CSR: (src, w) pairs per destination ----
__global__ void fill_kernel(const int* __restrict__ edge_index,
                            const int* __restrict__ edge_mask,
                            const float* __restrict__ edge_scale,
                            const float* __restrict__ pert_mask,
                            const float* __restrict__ edge_weight,
                            int* __restrict__ wp,
                            int2* __restrict__ e8) {
    const int e = blockIdx.x * 256 + threadIdx.x;
    if (e >= NEDGES) return;
    if (!edge_mask[e]) return;
    const float w = (edge_weight[e] * (1.0f - pert_mask[e]) + pert_mask[e]) * edge_scale[e];
    const int src = edge_index[e];
    const int dst = edge_index[NEDGES + e];
    const int pos = atomicAdd(&wp[dst], 1);
    e8[pos] = make_int2(src, __float_as_int(w));
}

// ---- gather + fused hardtanh update: 32 lanes per node, lane = feature ----
__global__ void gather_kernel(const float* __restrict__ x,
                              const int* __restrict__ row_ptr,
                              const int2* __restrict__ e8,
                              const float* __restrict__ S,
                              float* __restrict__ out) {
    const int gid = blockIdx.x * blockDim.x + threadIdx.x;
    const int node = gid >> 5;
    const int f = gid & 31;
    if (node >= NNODES) return;
    const int beg = row_ptr[node];
    const int end = row_ptr[node + 1];
    float acc = 0.0f;
    for (int e = beg; e < end; ++e) {
        const int2 sw = e8[e];                       // broadcast across the 32-lane group
        acc += __int_as_float(sw.y) * x[sw.x * FEAT + f];
    }
    if (node == 0) acc += S[0] * x[f];               // masked-edge bulk contribution
    const float xi = x[node * FEAT + f];
    const float d = fminf(fmaxf(acc - xi, -1.0f), 1.0f);
    out[node * FEAT + f] = fminf(fmaxf(xi + d, 0.0f), 2.0f);
}

extern "C" void kernel_launch(void* const* d_in, const int* in_sizes, int n_in,
                              void* d_out, int out_size, void* d_ws, size_t ws_size,
                              hipStream_t stream) {
    const float* x0         = (const float*)d_in[0];
    const int*   edge_index = (const int*)d_in[1];
    const int*   edge_mask  = (const int*)d_in[2];
    const float* edge_scale = (const float*)d_in[3];
    const float* pert_mask  = (const float*)d_in[4];
    const float* edge_weight= (const float*)d_in[5];
    float* xout = (float*)d_out;

    // ---- workspace layout ----
    char* ws = (char*)d_ws;
    float* S      = (float*)(ws);                       // 4 B
    float* S_part = (float*)(ws + 1024);                // 12500 floats (50 KB)
    int*   counts = (int*)(ws + 64 * 1024);             // NPAD ints (401 KB)
    int*   bsum   = (int*)(ws + 512 * 1024);            // 98 ints
    int*   boff   = (int*)(ws + 512 * 1024 + 1024);     // 98 ints
    int*   row_ptr= (int*)(ws + 768 * 1024);            // 100001 ints
    int*   wp     = (int*)(ws + 1536 * 1024);           // 100000 ints
    float* x_mid  = (float*)(ws + 2 * 1024 * 1024);     // NF floats (12.8 MB)
    int2*  e8     = (int2*)(ws + 16 * 1024 * 1024);     // up to NEDGES pairs (25.6 MB)

    // zero the histogram (NPAD ints; padding beyond NNODES stays 0 for the scan)
    hipMemsetAsync(counts, 0, (size_t)NPAD * sizeof(int), stream);

    hist_kernel<<<HIST_BLOCKS, 256, 0, stream>>>(edge_index, edge_mask, edge_scale,
                                                 pert_mask, edge_weight, counts, S_part);
    sreduce_kernel<<<1, 1024, 0, stream>>>(S_part, S);
    scan1_kernel<<<NB1, SCAN_BLK, 0, stream>>>(counts, bsum);
    scan2_kernel<<<1, 128, 0, stream>>>(bsum, boff);
    scan3_kernel<<<NB1, SCAN_BLK, 0, stream>>>(counts, boff, row_ptr, wp);
    fill_kernel<<<HIST_BLOCKS, 256, 0, stream>>>(edge_index, edge_mask, edge_scale,
                                                 pert_mask, edge_weight, wp, e8);

    // 5 gather iterations, ping-pong: x0 -> out -> mid -> out -> mid -> out
    const int gblocks = (NNODES * 32) / 256;   // 12500, exact
    const float* cur = x0;
    float* bufs[NITER] = { xout, x_mid, xout, x_mid, xout };
    for (int it = 0; it < NITER; ++it) {
        gather_kernel<<<gblocks, 256, 0, stream>>>(cur, row_ptr, e8, S, bufs[it]);
        cur = bufs[it];
    }
}

// Round 3
// 423.286 us; speedup vs baseline: 4.8934x; 1.4074x over previous
//
#include <hip/hip_runtime.h>

#define NNODES 100000
#define NEDGES 3200000
#define FEAT 32
#define NITER 5
#define NF (NNODES * FEAT)

#define SCAN_BLK 1024
#define NB1 98              // ceil(100000/1024); 98*1024 = 100352
#define NPAD (NB1 * SCAN_BLK)
#define EDGE_BLOCKS ((NEDGES + 255) / 256)   // 12500
#define MASKED_SENTINEL 0x7fffffff

// ---- pass A: dst histogram (unmasked) + per-edge weight store + masked-weight partials ----
__global__ void hist_kernel(const int* __restrict__ edge_index,
                            const int* __restrict__ edge_mask,
                            const float* __restrict__ edge_scale,
                            const float* __restrict__ pert_mask,
                            const float* __restrict__ edge_weight,
                            int* __restrict__ counts,
                            int* __restrict__ wbuf,
                            float* __restrict__ S_part) {
    const int e = blockIdx.x * 256 + threadIdx.x;
    float ms = 0.0f;
    if (e < NEDGES) {
        const int m = edge_mask[e];
        const float w = (edge_weight[e] * (1.0f - pert_mask[e]) + pert_mask[e]) * edge_scale[e];
        if (m) {
            atomicAdd(&counts[edge_index[NEDGES + e]], 1);
            wbuf[e] = __float_as_int(w);
        } else {
            wbuf[e] = MASKED_SENTINEL;
            ms = w;   // masked edge: contributes w * x[0] to node 0
        }
    }
    __shared__ float s[256];
    s[threadIdx.x] = ms;
    __syncthreads();
    for (int off = 128; off; off >>= 1) {
        if (threadIdx.x < off) s[threadIdx.x] += s[threadIdx.x + off];
        __syncthreads();
    }
    if (threadIdx.x == 0) S_part[blockIdx.x] = s[0];
}

// ---- deterministic reduce of S partials ----
__global__ void sreduce_kernel(const float* __restrict__ S_part, float* __restrict__ S) {
    __shared__ float s[1024];
    float a = 0.0f;
    for (int i = threadIdx.x; i < EDGE_BLOCKS; i += 1024) a += S_part[i];
    s[threadIdx.x] = a;
    __syncthreads();
    for (int off = 512; off; off >>= 1) {
        if (threadIdx.x < off) s[threadIdx.x] += s[threadIdx.x + off];
        __syncthreads();
    }
    if (threadIdx.x == 0) *S = s[0];
}

// ---- scan stage 1: per-block sums ----
__global__ void scan1_kernel(const int* __restrict__ counts, int* __restrict__ bsum) {
    __shared__ int s[SCAN_BLK];
    const int i = blockIdx.x * SCAN_BLK + threadIdx.x;
    s[threadIdx.x] = counts[i];
    __syncthreads();
    for (int off = SCAN_BLK / 2; off; off >>= 1) {
        if (threadIdx.x < off) s[threadIdx.x] += s[threadIdx.x + off];
        __syncthreads();
    }
    if (threadIdx.x == 0) bsum[blockIdx.x] = s[0];
}

// ---- scan stage 2: exclusive scan of block sums ----
__global__ void scan2_kernel(const int* __restrict__ bsum, int* __restrict__ boff) {
    __shared__ int s[128];
    const int tid = threadIdx.x;
    int v = (tid < NB1) ? bsum[tid] : 0;
    s[tid] = v;
    __syncthreads();
    for (int off = 1; off < 128; off <<= 1) {
        int t = (tid >= off) ? s[tid - off] : 0;
        __syncthreads();
        s[tid] += t;
        __syncthreads();
    }
    if (tid < NB1) boff[tid] = s[tid] - v;   // exclusive
}

// ---- scan stage 3: per-block exclusive scan + offset -> row_ptr, wp ----
__global__ void scan3_kernel(const int* __restrict__ counts, const int* __restrict__ boff,
                             int* __restrict__ row_ptr, int* __restrict__ wp) {
    __shared__ int s[SCAN_BLK];
    const int tid = threadIdx.x;
    const int i = blockIdx.x * SCAN_BLK + tid;
    const int v = counts[i];
    s[tid] = v;
    __syncthreads();
    for (int off = 1; off < SCAN_BLK; off <<= 1) {
        int t = (tid >= off) ? s[tid - off] : 0;
        __syncthreads();
        s[tid] += t;
        __syncthreads();
    }
    const int excl = boff[blockIdx.x] + s[tid] - v;
    if (i <= NNODES) row_ptr[i] = excl;
    if (i < NNODES)  wp[i] = excl;
}

// ---- fill CSR: (src, w) pairs per destination; w from wbuf (NaN-sentinel = masked) ----
__global__ void fill_kernel(const int* __restrict__ edge_index,
                            const int* __restrict__ wbuf,
                            int* __restrict__ wp,
                            int2* __restrict__ e8) {
    const int e = blockIdx.x * 256 + threadIdx.x;
    if (e >= NEDGES) return;
    const int wi = wbuf[e];
    if (wi == MASKED_SENTINEL) return;
    const int src = edge_index[e];
    const int dst = edge_index[NEDGES + e];
    const int pos = atomicAdd(&wp[dst], 1);
    e8[pos] = make_int2(src, wi);
}

// ---- gather + fused hardtanh update: 64 lanes (1 wave) per node ----
// lane = 32*h + f; half h processes 8-edge chunks at beg+8h, beg+8h+16, ...
#define CH 8
__global__ void gather_kernel(const float* __restrict__ x,
                              const int* __restrict__ row_ptr,
                              const int2* __restrict__ e8,
                              const float* __restrict__ S,
                              float* __restrict__ out) {
    const int gid = blockIdx.x * blockDim.x + threadIdx.x;
    const int node = gid >> 6;
    const int lane = threadIdx.x & 63;
    const int f = lane & 31;
    const int h = lane >> 5;
    if (node >= NNODES) return;
    const int beg = row_ptr[node];
    const int end = row_ptr[node + 1];
    const float xi = x[node * FEAT + f];

    float a0 = 0.0f, a1 = 0.0f;
    const int em1 = end - 1;
    for (int e = beg + CH * h; e < end; e += 2 * CH) {
        int2 s[CH];
        #pragma unroll
        for (int k = 0; k < CH; ++k) s[k] = e8[min(e + k, em1)];
        #pragma unroll
        for (int k = 0; k < CH; ++k) {
            const float v = x[s[k].x * FEAT + f];
            const float w = (e + k < end) ? __int_as_float(s[k].y) : 0.0f;
            if (k & 1) a1 = fmaf(w, v, a1);
            else       a0 = fmaf(w, v, a0);
        }
    }
    float acc = a0 + a1;
    acc += __shfl_xor(acc, 32);          // combine the two halves
    if (node == 0) acc += S[0] * x[f];   // masked-edge bulk contribution
    const float d = fminf(fmaxf(acc - xi, -1.0f), 1.0f);
    if (h == 0) out[node * FEAT + f] = fminf(fmaxf(xi + d, 0.0f), 2.0f);
}

extern "C" void kernel_launch(void* const* d_in, const int* in_sizes, int n_in,
                              void* d_out, int out_size, void* d_ws, size_t ws_size,
                              hipStream_t stream) {
    const float* x0         = (const float*)d_in[0];
    const int*   edge_index = (const int*)d_in[1];
    const int*   edge_mask  = (const int*)d_in[2];
    const float* edge_scale = (const float*)d_in[3];
    const float* pert_mask  = (const float*)d_in[4];
    const float* edge_weight= (const float*)d_in[5];
    float* xout = (float*)d_out;

    // ---- workspace layout ----
    char* ws = (char*)d_ws;
    float* S      = (float*)(ws);                       // 4 B
    float* S_part = (float*)(ws + 1024);                // 12500 floats (50 KB)
    int*   counts = (int*)(ws + 64 * 1024);             // NPAD ints (401 KB)
    int*   bsum   = (int*)(ws + 512 * 1024);            // 98 ints
    int*   boff   = (int*)(ws + 512 * 1024 + 1024);     // 98 ints
    int*   row_ptr= (int*)(ws + 768 * 1024);            // 100001 ints
    int*   wp     = (int*)(ws + 1536 * 1024);           // 100000 ints
    float* x_mid  = (float*)(ws + 2 * 1024 * 1024);     // NF floats (12.8 MB)
    int2*  e8     = (int2*)(ws + 16 * 1024 * 1024);     // up to NEDGES pairs (25.6 MB)
    int*   wbuf   = (int*)(ws + 48 * 1024 * 1024);      // NEDGES ints (12.8 MB)
    // total ~60.8 MB

    hipMemsetAsync(counts, 0, (size_t)NPAD * sizeof(int), stream);

    hist_kernel<<<EDGE_BLOCKS, 256, 0, stream>>>(edge_index, edge_mask, edge_scale,
                                                 pert_mask, edge_weight, counts, wbuf, S_part);
    sreduce_kernel<<<1, 1024, 0, stream>>>(S_part, S);
    scan1_kernel<<<NB1, SCAN_BLK, 0, stream>>>(counts, bsum);
    scan2_kernel<<<1, 128, 0, stream>>>(bsum, boff);
    scan3_kernel<<<NB1, SCAN_BLK, 0, stream>>>(counts, boff, row_ptr, wp);
    fill_kernel<<<EDGE_BLOCKS, 256, 0, stream>>>(edge_index, wbuf, wp, e8);

    // 5 gather iterations, ping-pong: x0 -> out -> mid -> out -> mid -> out
    const int gblocks = (NNODES * 64) / 256;   // 25000, exact
    const float* cur = x0;
    float* bufs[NITER] = { xout, x_mid, xout, x_mid, xout };
    for (int it = 0; it < NITER; ++it) {
        gather_kernel<<<gblocks, 256, 0, stream>>>(cur, row_ptr, e8, S, bufs[it]);
        cur = bufs[it];
    }
}